// Round 7
// baseline (704.498 us; speedup 1.0000x reference)
//
#include <hip/hip_runtime.h>
#include <math.h>

#define N_NODES 20000
#define M_PAD   20096   // 157 * 128
#define N_EDGES 320000
#define DIM_IN 768
#define DIM_H 512
#define NUM_GNNS 4
#define NEG_SLOPE 0.2f
#define NEG_HUGE -3.0e38f   // finite softmax identity: -INF breaks online merge (-inf - -inf = NaN)

typedef __attribute__((ext_vector_type(8))) short short8;
typedef __attribute__((ext_vector_type(4))) float f32x4;

#define GPTR(p) (const __attribute__((address_space(1))) void*)(p)
#define LPTR(p) (__attribute__((address_space(3))) void*)(p)

__device__ __forceinline__ float bf2f(unsigned int lo16) {
  return __uint_as_float(lo16 << 16);
}
__device__ __forceinline__ unsigned short f2bf(float f) {
  unsigned int u = __float_as_uint(f);
  u += 0x7FFFu + ((u >> 16) & 1u);   // round-to-nearest-even
  return (unsigned short)(u >> 16);
}
__device__ __forceinline__ void unpack8(uint4 v, float* f) {
  f[0] = bf2f(v.x & 0xffffu); f[1] = bf2f(v.x >> 16);
  f[2] = bf2f(v.y & 0xffffu); f[3] = bf2f(v.y >> 16);
  f[4] = bf2f(v.z & 0xffffu); f[5] = bf2f(v.z >> 16);
  f[6] = bf2f(v.w & 0xffffu); f[7] = bf2f(v.w >> 16);
}
__device__ __forceinline__ uint4 pack8(const float* o) {
  uint4 pv;
  pv.x = (unsigned)f2bf(o[0]) | ((unsigned)f2bf(o[1]) << 16);
  pv.y = (unsigned)f2bf(o[2]) | ((unsigned)f2bf(o[3]) << 16);
  pv.z = (unsigned)f2bf(o[4]) | ((unsigned)f2bf(o[5]) << 16);
  pv.w = (unsigned)f2bf(o[6]) | ((unsigned)f2bf(o[7]) << 16);
  return pv;
}

// ================= MFMA GEMM + fused el/er epilogue =================
// Cbf[M_PAD,512](bf16) = A[M_PAD,K](bf16) @ Bt[512,K]^T (+bias)
// If al != nullptr: el[row] += sum_col z*al[col], er likewise (atomicAdd).
__global__ __launch_bounds__(256) void gemm_mfma_bf16(
    const unsigned short* __restrict__ A,
    const unsigned short* __restrict__ Bt,
    const float* __restrict__ bias,
    unsigned short* __restrict__ Cbf,
    int K,
    const float* __restrict__ al, const float* __restrict__ ar,
    float* __restrict__ el, float* __restrict__ er) {
  __shared__ __align__(16) unsigned short As[128 * 32];
  __shared__ __align__(16) unsigned short Bs[128 * 32];
  int tid = threadIdx.x;
  int wave = tid >> 6, lane = tid & 63;
  int wm = wave >> 1, wn = wave & 1;

  int rl = lane >> 2;
  int kc = (lane & 3) ^ ((lane >> 3) & 3);
  int r0 = 32 * wave;
  const unsigned short* gA0 = A + (size_t)(blockIdx.y * 128 + r0 + rl) * K + kc * 8;
  const unsigned short* gA1 = gA0 + (size_t)16 * K;
  const unsigned short* gB0 = Bt + (size_t)(blockIdx.x * 128 + r0 + rl) * K + kc * 8;
  const unsigned short* gB1 = gB0 + (size_t)16 * K;
  unsigned short* lA0 = As + r0 * 32;
  unsigned short* lA1 = As + (r0 + 16) * 32;
  unsigned short* lB0 = Bs + r0 * 32;
  unsigned short* lB1 = Bs + (r0 + 16) * 32;

  int mrow = lane & 15;
  int q = lane >> 4;
  int swz = (q ^ ((mrow >> 1) & 3)) * 8;
  const short8* ra = (const short8*)(As + (64 * wm + mrow) * 32 + swz);
  const short8* rb = (const short8*)(Bs + (64 * wn + mrow) * 32 + swz);

  f32x4 acc[4][4];
#pragma unroll
  for (int i = 0; i < 4; ++i)
#pragma unroll
    for (int j = 0; j < 4; ++j) acc[i][j] = (f32x4)(0.f);

  for (int k0 = 0; k0 < K; k0 += 32) {
    __syncthreads();
    __builtin_amdgcn_global_load_lds(GPTR(gA0 + k0), LPTR(lA0), 16, 0, 0);
    __builtin_amdgcn_global_load_lds(GPTR(gA1 + k0), LPTR(lA1), 16, 0, 0);
    __builtin_amdgcn_global_load_lds(GPTR(gB0 + k0), LPTR(lB0), 16, 0, 0);
    __builtin_amdgcn_global_load_lds(GPTR(gB1 + k0), LPTR(lB1), 16, 0, 0);
    __syncthreads();
    short8 a[4], b[4];
#pragma unroll
    for (int t = 0; t < 4; ++t) a[t] = ra[t * 64];
#pragma unroll
    for (int t = 0; t < 4; ++t) b[t] = rb[t * 64];
#pragma unroll
    for (int mt = 0; mt < 4; ++mt)
#pragma unroll
      for (int nt = 0; nt < 4; ++nt)
        acc[mt][nt] = __builtin_amdgcn_mfma_f32_16x16x32_bf16(a[mt], b[nt], acc[mt][nt], 0, 0, 0);
  }

  int colb = blockIdx.x * 128 + 64 * wn + (lane & 15);
  int rowb = blockIdx.y * 128 + 64 * wm + 4 * q;

  // ---- C store (+bias) ----
#pragma unroll
  for (int nt = 0; nt < 4; ++nt) {
    int col = colb + 16 * nt;
    float bv = bias ? bias[col] : 0.f;
#pragma unroll
    for (int mt = 0; mt < 4; ++mt) {
      int row = rowb + 16 * mt;
#pragma unroll
      for (int i = 0; i < 4; ++i)
        Cbf[(size_t)(row + i) * DIM_H + col] = f2bf(acc[mt][nt][i] + bv);
    }
  }

  // ---- fused el/er partial reduction ----
  if (al) {
    float alv[4], arv[4];
#pragma unroll
    for (int nt = 0; nt < 4; ++nt) {
      alv[nt] = al[colb + 16 * nt];
      arv[nt] = ar[colb + 16 * nt];
    }
#pragma unroll
    for (int mt = 0; mt < 4; ++mt) {
#pragma unroll
      for (int i = 0; i < 4; ++i) {
        float pl = acc[mt][0][i] * alv[0] + acc[mt][1][i] * alv[1] +
                   acc[mt][2][i] * alv[2] + acc[mt][3][i] * alv[3];
        float pr = acc[mt][0][i] * arv[0] + acc[mt][1][i] * arv[1] +
                   acc[mt][2][i] * arv[2] + acc[mt][3][i] * arv[3];
#pragma unroll
        for (int msk = 1; msk < 16; msk <<= 1) {
          pl += __shfl_xor(pl, msk, 64);
          pr += __shfl_xor(pr, msk, 64);
        }
        if ((lane & 15) == 0) {
          int row = rowb + 16 * mt + i;   // row < M_PAD; el/er sized M_PAD
          atomicAdd(&el[row], pl);
          atomicAdd(&er[row], pr);
        }
      }
    }
  }
}

// ================= conversions =================
__global__ void convert_feat(const float* __restrict__ feat, unsigned short* __restrict__ Abf) {
  int t = blockIdx.x * blockDim.x + threadIdx.x;
  const int CHUNKS = M_PAD * DIM_IN / 8;
  if (t >= CHUNKS) return;
  int row = t / (DIM_IN / 8);
  uint4 o;
  if (row < N_NODES) {
    const float4* p = (const float4*)(feat + (size_t)t * 8);
    float4 x = p[0], y = p[1];
    o.x = (unsigned)f2bf(x.x) | ((unsigned)f2bf(x.y) << 16);
    o.y = (unsigned)f2bf(x.z) | ((unsigned)f2bf(x.w) << 16);
    o.z = (unsigned)f2bf(y.x) | ((unsigned)f2bf(y.y) << 16);
    o.w = (unsigned)f2bf(y.z) | ((unsigned)f2bf(y.w) << 16);
  } else {
    o = make_uint4(0, 0, 0, 0);
  }
  ((uint4*)Abf)[t] = o;
}

__global__ void transpose_bf16(const float* __restrict__ in, unsigned short* __restrict__ out,
                               int R, int C) {
  int r = blockIdx.x * blockDim.x + threadIdx.x;
  int c = blockIdx.y;
  size_t base = (size_t)blockIdx.z * R * C;
  if (r < R) out[base + (size_t)c * R + r] = f2bf(in[base + (size_t)r * C + c]);
}

// ================= CSR build (dst -> src adjacency) =================
__global__ void count_edges(const int* __restrict__ dst, int* __restrict__ counts) {
  int k = blockIdx.x * blockDim.x + threadIdx.x;
  if (k < N_EDGES) atomicAdd(&counts[dst[k]], 1);
}

__global__ __launch_bounds__(1024) void scan_kernel(const int* __restrict__ counts,
                                                    int* __restrict__ indptr) {
  __shared__ int part[1024];
  int tid = threadIdx.x;
  const int CH = (N_NODES + 1023) / 1024;
  int base = tid * CH;
  int s = 0;
  for (int i = 0; i < CH; ++i) {
    int idx = base + i;
    if (idx < N_NODES) s += counts[idx];
  }
  part[tid] = s;
  __syncthreads();
  for (int off = 1; off < 1024; off <<= 1) {
    int v = (tid >= off) ? part[tid - off] : 0;
    __syncthreads();
    part[tid] += v;
    __syncthreads();
  }
  int run = (tid == 0) ? 0 : part[tid - 1];
  for (int i = 0; i < CH; ++i) {
    int idx = base + i;
    if (idx < N_NODES) {
      indptr[idx] = run;
      run += counts[idx];
      if (idx == N_NODES - 1) indptr[N_NODES] = run;
    }
  }
}

__global__ void fill_adj(const int* __restrict__ src, const int* __restrict__ dst,
                         const int* __restrict__ indptr, int* __restrict__ cursor,
                         int* __restrict__ adjsrc) {
  int k = blockIdx.x * blockDim.x + threadIdx.x;
  if (k < N_EDGES) {
    int d = dst[k];
    int pos = atomicAdd(&cursor[d], 1);
    adjsrc[indptr[d] + pos] = src[k];
  }
}

// ================= GAT edge softmax + aggregate (wave per dst), bf16 payload =================
// Online softmax (single el pass, finite identity) + 8 row-gathers in flight.
__global__ __launch_bounds__(256) void gat_aggregate_bf(
    const unsigned short* __restrict__ zbf, const float* __restrict__ el,
    const float* __restrict__ er, const int* __restrict__ indptr,
    const int* __restrict__ adjsrc, const float* __restrict__ bias,
    unsigned short* __restrict__ out_bf) {
  int v = (blockIdx.x * blockDim.x + threadIdx.x) >> 6;
  int lane = threadIdx.x & 63;
  if (v >= N_NODES) return;
  int begin = indptr[v], end = indptr[v + 1];
  float er_v = er[v];

  // online (max, sum) in one strided pass; NEG_HUGE (finite) so empty-lane
  // merges compute exp(0)=1 instead of exp(-inf - -inf)=NaN.
  float m = NEG_HUGE, ssum = 0.f;
  for (int j = begin + lane; j < end; j += 64) {
    float e = el[adjsrc[j]] + er_v;
    e = (e >= 0.f) ? e : NEG_SLOPE * e;
    float nm = fmaxf(m, e);
    ssum = ssum * __expf(m - nm) + __expf(e - nm);
    m = nm;
  }
#pragma unroll
  for (int off = 32; off > 0; off >>= 1) {
    float om = __shfl_xor(m, off, 64);
    float os = __shfl_xor(ssum, off, 64);
    float nm = fmaxf(m, om);
    ssum = ssum * __expf(m - nm) + os * __expf(om - nm);
    m = nm;
  }
  float inv = (end > begin) ? 1.f / ssum : 0.f;

  // weighted accumulate, 8 rows in flight
  float acc[8] = {};
  for (int c = begin; c < end; c += 64) {
    int cc = min(64, end - c);
    int has = (c + lane < end);
    int sIdx = has ? adjsrc[c + lane] : 0;
    float e = has ? el[sIdx] + er_v : 0.f;
    e = (e >= 0.f) ? e : NEG_SLOPE * e;
    float wl = has ? __expf(e - m) * inv : 0.f;
    int t = 0;
    for (; t + 8 <= cc; t += 8) {
      uint4 z[8];
      float w[8];
#pragma unroll
      for (int u = 0; u < 8; ++u) {
        int s = __shfl(sIdx, t + u);
        w[u] = __shfl(wl, t + u);
        z[u] = ((const uint4*)(zbf + (size_t)s * DIM_H))[lane];
      }
#pragma unroll
      for (int u = 0; u < 8; ++u) {
        float f[8];
        unpack8(z[u], f);
#pragma unroll
        for (int i = 0; i < 8; ++i) acc[i] += w[u] * f[i];
      }
    }
    for (; t + 4 <= cc; t += 4) {
      uint4 z[4];
      float w[4];
#pragma unroll
      for (int u = 0; u < 4; ++u) {
        int s = __shfl(sIdx, t + u);
        w[u] = __shfl(wl, t + u);
        z[u] = ((const uint4*)(zbf + (size_t)s * DIM_H))[lane];
      }
#pragma unroll
      for (int u = 0; u < 4; ++u) {
        float f[8];
        unpack8(z[u], f);
#pragma unroll
        for (int i = 0; i < 8; ++i) acc[i] += w[u] * f[i];
      }
    }
    for (; t < cc; ++t) {
      int s0 = __shfl(sIdx, t);
      float w0 = __shfl(wl, t);
      uint4 z0 = ((const uint4*)(zbf + (size_t)s0 * DIM_H))[lane];
      float f0[8];
      unpack8(z0, f0);
#pragma unroll
      for (int i = 0; i < 8; ++i) acc[i] += w0 * f0[i];
    }
  }
  const float4* b4 = (const float4*)(bias + lane * 8);
  float4 b0 = b4[0], b1 = b4[1];
  float o[8] = {acc[0] + b0.x, acc[1] + b0.y, acc[2] + b0.z, acc[3] + b0.w,
                acc[4] + b1.x, acc[5] + b1.y, acc[6] + b1.z, acc[7] + b1.w};
  ((uint4*)(out_bf + (size_t)v * DIM_H))[lane] = pack8(o);
}

// ======== A_hat hop (bf16 payload, fp32 accumulate), 8 rows in flight ========
__global__ __launch_bounds__(256) void propagate_bf(const unsigned short* __restrict__ zin,
                                                    const int* __restrict__ indptr,
                                                    const int* __restrict__ adjsrc,
                                                    unsigned short* __restrict__ out_bf,
                                                    float* __restrict__ out_f32) {
  int v = (blockIdx.x * blockDim.x + threadIdx.x) >> 6;
  int lane = threadIdx.x & 63;
  if (v >= N_NODES) return;
  uint4 sv = ((const uint4*)(zin + (size_t)v * DIM_H))[lane];
  float acc[8];
  unpack8(sv, acc);
  int begin = indptr[v], end = indptr[v + 1];
  for (int c = begin; c < end; c += 64) {
    int cc = min(64, end - c);
    int sIdx = (c + lane < end) ? adjsrc[c + lane] : 0;
    int t = 0;
    for (; t + 8 <= cc; t += 8) {
      uint4 z[8];
#pragma unroll
      for (int u = 0; u < 8; ++u) {
        int s = __shfl(sIdx, t + u);
        z[u] = ((const uint4*)(zin + (size_t)s * DIM_H))[lane];
      }
#pragma unroll
      for (int u = 0; u < 8; ++u) {
        float f[8];
        unpack8(z[u], f);
#pragma unroll
        for (int i = 0; i < 8; ++i) acc[i] += f[i];
      }
    }
    for (; t + 4 <= cc; t += 4) {
      uint4 z[4];
#pragma unroll
      for (int u = 0; u < 4; ++u) {
        int s = __shfl(sIdx, t + u);
        z[u] = ((const uint4*)(zin + (size_t)s * DIM_H))[lane];
      }
#pragma unroll
      for (int u = 0; u < 4; ++u) {
        float f[8];
        unpack8(z[u], f);
#pragma unroll
        for (int i = 0; i < 8; ++i) acc[i] += f[i];
      }
    }
    for (; t < cc; ++t) {
      int s0 = __shfl(sIdx, t);
      uint4 z0 = ((const uint4*)(zin + (size_t)s0 * DIM_H))[lane];
      float f0[8];
      unpack8(z0, f0);
#pragma unroll
      for (int i = 0; i < 8; ++i) acc[i] += f0[i];
    }
  }
  if (out_bf) {
    ((uint4*)(out_bf + (size_t)v * DIM_H))[lane] = pack8(acc);
  } else {
    float4* fr = (float4*)(out_f32 + (size_t)v * DIM_H + lane * 8);
    fr[0] = make_float4(acc[0], acc[1], acc[2], acc[3]);
    fr[1] = make_float4(acc[4], acc[5], acc[6], acc[7]);
  }
}

// ================= launch =================
extern "C" void kernel_launch(void* const* d_in, const int* in_sizes, int n_in,
                              void* d_out, int out_size, void* d_ws, size_t ws_size,
                              hipStream_t stream) {
  const float* feat = (const float*)d_in[0];
  const float* fc_W = (const float*)d_in[1];
  const float* fc_b = (const float*)d_in[2];
  const float* gat_W = (const float*)d_in[3];
  const float* gat_al = (const float*)d_in[4];
  const float* gat_ar = (const float*)d_in[5];
  const float* gat_b = (const float*)d_in[6];
  // d_in[7] = beta unused (reference returns Z_prev)
  const int* src = (const int*)d_in[8];
  const int* dst = (const int*)d_in[9];
  float* out = (float*)d_out;

  char* w = (char*)d_ws;
  auto alloc = [&](size_t bytes) {
    char* p = w;
    w += (bytes + 255) & ~(size_t)255;
    return p;
  };
  unsigned short* hbf   = (unsigned short*)alloc((size_t)M_PAD * DIM_H * 2);
  unsigned short* fcWt  = (unsigned short*)alloc((size_t)DIM_H * DIM_IN * 2);
  unsigned short* gatWt = (unsigned short*)alloc((size_t)NUM_GNNS * DIM_H * DIM_H * 2);
  // el+er contiguous (single memset), sized M_PAD: padded GEMM rows write here
  float* el    = (float*)alloc((size_t)2 * M_PAD * 4);
  float* er    = el + M_PAD;
  int* counts  = (int*)alloc((size_t)2 * N_NODES * 4);   // counts+cursor contiguous (R2 lesson)
  int* cursor  = counts + N_NODES;
  int* indptr  = (int*)alloc((size_t)(N_NODES + 1) * 4);
  int* adjsrc  = (int*)alloc((size_t)N_EDGES * 4);
  char* uni = alloc((size_t)M_PAD * DIM_IN * 2);   // Abf (30.9 MB), later Z1 (20.6 MB)
  unsigned short* Abf = (unsigned short*)uni;
  unsigned short* Z1  = (unsigned short*)uni;
  unsigned short* zbf = (unsigned short*)d_out;

  // ---- CSR build ----
  hipMemsetAsync(counts, 0, sizeof(int) * 2 * N_NODES, stream);
  count_edges<<<(N_EDGES + 255) / 256, 256, 0, stream>>>(dst, counts);
  scan_kernel<<<1, 1024, 0, stream>>>(counts, indptr);
  fill_adj<<<(N_EDGES + 255) / 256, 256, 0, stream>>>(src, dst, indptr, cursor, adjsrc);

  // ---- bf16 prep ----
  convert_feat<<<(M_PAD * DIM_IN / 8 + 255) / 256, 256, 0, stream>>>(feat, Abf);
  transpose_bf16<<<dim3((DIM_IN + 255) / 256, DIM_H, 1), 256, 0, stream>>>(fc_W, fcWt, DIM_IN, DIM_H);
  transpose_bf16<<<dim3((DIM_H + 255) / 256, DIM_H, NUM_GNNS), 256, 0, stream>>>(gat_W, gatWt, DIM_H, DIM_H);

  dim3 ggrid(DIM_H / 128, M_PAD / 128);  // (4, 157)

  gemm_mfma_bf16<<<ggrid, 256, 0, stream>>>(Abf, fcWt, fc_b, hbf, DIM_IN,
                                            nullptr, nullptr, nullptr, nullptr);

  int nwaveblocks = (N_NODES * 64 + 255) / 256;
  for (int l = 0; l < NUM_GNNS; ++l) {
    hipMemsetAsync(el, 0, sizeof(float) * 2 * M_PAD, stream);
    gemm_mfma_bf16<<<ggrid, 256, 0, stream>>>(hbf, gatWt + (size_t)l * DIM_H * DIM_H,
                                              nullptr, zbf, DIM_H,
                                              gat_al + (size_t)l * DIM_H,
                                              gat_ar + (size_t)l * DIM_H, el, er);
    gat_aggregate_bf<<<nwaveblocks, 256, 0, stream>>>(
        zbf, el, er, indptr, adjsrc, gat_b + (size_t)l * DIM_H, hbf);
  }

  // ---- 3 propagation hops, bf16 payloads, fp32 accumulate ----
  propagate_bf<<<nwaveblocks, 256, 0, stream>>>(hbf, indptr, adjsrc, Z1, nullptr);
  propagate_bf<<<nwaveblocks, 256, 0, stream>>>(Z1, indptr, adjsrc, hbf, nullptr);
  propagate_bf<<<nwaveblocks, 256, 0, stream>>>(hbf, indptr, adjsrc, nullptr, out);
}

// Round 8
// 697.592 us; speedup vs baseline: 1.0099x; 1.0099x over previous
//
#include <hip/hip_runtime.h>
#include <math.h>

#define N_NODES 20000
#define M_PAD   20096   // 157 * 128
#define N_EDGES 320000
#define DIM_IN 768
#define DIM_H 512
#define NUM_GNNS 4
#define NEG_SLOPE 0.2f

typedef __attribute__((ext_vector_type(8))) short short8;
typedef __attribute__((ext_vector_type(4))) float f32x4;

#define GPTR(p) (const __attribute__((address_space(1))) void*)(p)
#define LPTR(p) (__attribute__((address_space(3))) void*)(p)

__device__ __forceinline__ float bf2f(unsigned int lo16) {
  return __uint_as_float(lo16 << 16);
}
__device__ __forceinline__ unsigned short f2bf(float f) {
  unsigned int u = __float_as_uint(f);
  u += 0x7FFFu + ((u >> 16) & 1u);   // round-to-nearest-even
  return (unsigned short)(u >> 16);
}
__device__ __forceinline__ void unpack8(uint4 v, float* f) {
  f[0] = bf2f(v.x & 0xffffu); f[1] = bf2f(v.x >> 16);
  f[2] = bf2f(v.y & 0xffffu); f[3] = bf2f(v.y >> 16);
  f[4] = bf2f(v.z & 0xffffu); f[5] = bf2f(v.z >> 16);
  f[6] = bf2f(v.w & 0xffffu); f[7] = bf2f(v.w >> 16);
}
__device__ __forceinline__ uint4 pack8(const float* o) {
  uint4 pv;
  pv.x = (unsigned)f2bf(o[0]) | ((unsigned)f2bf(o[1]) << 16);
  pv.y = (unsigned)f2bf(o[2]) | ((unsigned)f2bf(o[3]) << 16);
  pv.z = (unsigned)f2bf(o[4]) | ((unsigned)f2bf(o[5]) << 16);
  pv.w = (unsigned)f2bf(o[6]) | ((unsigned)f2bf(o[7]) << 16);
  return pv;
}

__device__ __forceinline__ float waveReduceSum(float v) {
#pragma unroll
  for (int off = 32; off > 0; off >>= 1) v += __shfl_xor(v, off, 64);
  return v;
}
__device__ __forceinline__ float waveReduceMax(float v) {
#pragma unroll
  for (int off = 32; off > 0; off >>= 1) v = fmaxf(v, __shfl_xor(v, off, 64));
  return v;
}

// ================= MFMA GEMM + fused el/er PARTIAL stores (no atomics) =================
// Cbf[M_PAD,512](bf16) = A[M_PAD,K](bf16) @ Bt[512,K]^T (+bias)
// If al != nullptr: elp[blockIdx.x*M_PAD + row] = sum over this block's 128 cols of z*al[col];
// erp likewise. A separate 2 µs reduce kernel sums the 4 column-block partials.
// (R7 lesson: atomicAdd-based fusion regressed; plain partial stores instead.)
__global__ __launch_bounds__(256) void gemm_mfma_bf16(
    const unsigned short* __restrict__ A,
    const unsigned short* __restrict__ Bt,
    const float* __restrict__ bias,
    unsigned short* __restrict__ Cbf,
    int K,
    const float* __restrict__ al, const float* __restrict__ ar,
    float* __restrict__ elp, float* __restrict__ erp) {
  __shared__ __align__(16) unsigned short As[128 * 32];
  __shared__ __align__(16) unsigned short Bs[128 * 32];
  int tid = threadIdx.x;
  int wave = tid >> 6, lane = tid & 63;
  int wm = wave >> 1, wn = wave & 1;

  int rl = lane >> 2;
  int kc = (lane & 3) ^ ((lane >> 3) & 3);
  int r0 = 32 * wave;
  const unsigned short* gA0 = A + (size_t)(blockIdx.y * 128 + r0 + rl) * K + kc * 8;
  const unsigned short* gA1 = gA0 + (size_t)16 * K;
  const unsigned short* gB0 = Bt + (size_t)(blockIdx.x * 128 + r0 + rl) * K + kc * 8;
  const unsigned short* gB1 = gB0 + (size_t)16 * K;
  unsigned short* lA0 = As + r0 * 32;
  unsigned short* lA1 = As + (r0 + 16) * 32;
  unsigned short* lB0 = Bs + r0 * 32;
  unsigned short* lB1 = Bs + (r0 + 16) * 32;

  int mrow = lane & 15;
  int q = lane >> 4;
  int swz = (q ^ ((mrow >> 1) & 3)) * 8;
  const short8* ra = (const short8*)(As + (64 * wm + mrow) * 32 + swz);
  const short8* rb = (const short8*)(Bs + (64 * wn + mrow) * 32 + swz);

  f32x4 acc[4][4];
#pragma unroll
  for (int i = 0; i < 4; ++i)
#pragma unroll
    for (int j = 0; j < 4; ++j) acc[i][j] = (f32x4)(0.f);

  for (int k0 = 0; k0 < K; k0 += 32) {
    __syncthreads();
    __builtin_amdgcn_global_load_lds(GPTR(gA0 + k0), LPTR(lA0), 16, 0, 0);
    __builtin_amdgcn_global_load_lds(GPTR(gA1 + k0), LPTR(lA1), 16, 0, 0);
    __builtin_amdgcn_global_load_lds(GPTR(gB0 + k0), LPTR(lB0), 16, 0, 0);
    __builtin_amdgcn_global_load_lds(GPTR(gB1 + k0), LPTR(lB1), 16, 0, 0);
    __syncthreads();
    short8 a[4], b[4];
#pragma unroll
    for (int t = 0; t < 4; ++t) a[t] = ra[t * 64];
#pragma unroll
    for (int t = 0; t < 4; ++t) b[t] = rb[t * 64];
#pragma unroll
    for (int mt = 0; mt < 4; ++mt)
#pragma unroll
      for (int nt = 0; nt < 4; ++nt)
        acc[mt][nt] = __builtin_amdgcn_mfma_f32_16x16x32_bf16(a[mt], b[nt], acc[mt][nt], 0, 0, 0);
  }

  int colb = blockIdx.x * 128 + 64 * wn + (lane & 15);
  int rowb = blockIdx.y * 128 + 64 * wm + 4 * q;

  // ---- C store (+bias) ----
#pragma unroll
  for (int nt = 0; nt < 4; ++nt) {
    int col = colb + 16 * nt;
    float bv = bias ? bias[col] : 0.f;
#pragma unroll
    for (int mt = 0; mt < 4; ++mt) {
      int row = rowb + 16 * mt;
#pragma unroll
      for (int i = 0; i < 4; ++i)
        Cbf[(size_t)(row + i) * DIM_H + col] = f2bf(acc[mt][nt][i] + bv);
    }
  }

  // ---- fused el/er: per-column-block partials, plain stores ----
  if (al) {
    float* elpb = elp + (size_t)blockIdx.x * M_PAD;
    float* erpb = erp + (size_t)blockIdx.x * M_PAD;
    float alv[4], arv[4];
#pragma unroll
    for (int nt = 0; nt < 4; ++nt) {
      alv[nt] = al[colb + 16 * nt];
      arv[nt] = ar[colb + 16 * nt];
    }
    // the two waves sharing wm (wn=0/1) each cover disjoint col halves of the
    // same rows -> each writes its own partial; combine wn into the block slot
    // by letting wn=0 store to elpb and wn=1 ADD via a second slot: instead,
    // keep it simple: partials indexed by (blockIdx.x*2 + wn) would need 8 slots.
    // Cheaper: reduce across the two waves through LDS? Avoid: use 8 slots.
#pragma unroll
    for (int mt = 0; mt < 4; ++mt) {
#pragma unroll
      for (int i = 0; i < 4; ++i) {
        float pl = acc[mt][0][i] * alv[0] + acc[mt][1][i] * alv[1] +
                   acc[mt][2][i] * alv[2] + acc[mt][3][i] * alv[3];
        float pr = acc[mt][0][i] * arv[0] + acc[mt][1][i] * arv[1] +
                   acc[mt][2][i] * arv[2] + acc[mt][3][i] * arv[3];
#pragma unroll
        for (int msk = 1; msk < 16; msk <<= 1) {
          pl += __shfl_xor(pl, msk, 64);
          pr += __shfl_xor(pr, msk, 64);
        }
        if ((lane & 15) == 0) {
          int row = rowb + 16 * mt + i;
          // 8 partial slots: [blockIdx.x*2 + wn]
          elpb[(size_t)wn * 4 * M_PAD + row] = pl;   // see layout note in launch
          erpb[(size_t)wn * 4 * M_PAD + row] = pr;
        }
      }
    }
  }
}

// sum the 8 partial slots -> el, er
__global__ void eler_reduce(const float* __restrict__ elp, const float* __restrict__ erp,
                            float* __restrict__ el, float* __restrict__ er) {
  int v = blockIdx.x * blockDim.x + threadIdx.x;
  if (v >= N_NODES) return;
  float sl = 0.f, sr = 0.f;
#pragma unroll
  for (int b = 0; b < 8; ++b) {
    sl += elp[(size_t)b * M_PAD + v];
    sr += erp[(size_t)b * M_PAD + v];
  }
  el[v] = sl;
  er[v] = sr;
}

// ================= conversions =================
__global__ void convert_feat(const float* __restrict__ feat, unsigned short* __restrict__ Abf) {
  int t = blockIdx.x * blockDim.x + threadIdx.x;
  const int CHUNKS = M_PAD * DIM_IN / 8;
  if (t >= CHUNKS) return;
  int row = t / (DIM_IN / 8);
  uint4 o;
  if (row < N_NODES) {
    const float4* p = (const float4*)(feat + (size_t)t * 8);
    float4 x = p[0], y = p[1];
    o.x = (unsigned)f2bf(x.x) | ((unsigned)f2bf(x.y) << 16);
    o.y = (unsigned)f2bf(x.z) | ((unsigned)f2bf(x.w) << 16);
    o.z = (unsigned)f2bf(y.x) | ((unsigned)f2bf(y.y) << 16);
    o.w = (unsigned)f2bf(y.z) | ((unsigned)f2bf(y.w) << 16);
  } else {
    o = make_uint4(0, 0, 0, 0);
  }
  ((uint4*)Abf)[t] = o;
}

__global__ void transpose_bf16(const float* __restrict__ in, unsigned short* __restrict__ out,
                               int R, int C) {
  int r = blockIdx.x * blockDim.x + threadIdx.x;
  int c = blockIdx.y;
  size_t base = (size_t)blockIdx.z * R * C;
  if (r < R) out[base + (size_t)c * R + r] = f2bf(in[base + (size_t)r * C + c]);
}

// ================= CSR build (dst -> src adjacency) =================
__global__ void count_edges(const int* __restrict__ dst, int* __restrict__ counts) {
  int k = blockIdx.x * blockDim.x + threadIdx.x;
  if (k < N_EDGES) atomicAdd(&counts[dst[k]], 1);
}

__global__ __launch_bounds__(1024) void scan_kernel(const int* __restrict__ counts,
                                                    int* __restrict__ indptr) {
  __shared__ int part[1024];
  int tid = threadIdx.x;
  const int CH = (N_NODES + 1023) / 1024;
  int base = tid * CH;
  int s = 0;
  for (int i = 0; i < CH; ++i) {
    int idx = base + i;
    if (idx < N_NODES) s += counts[idx];
  }
  part[tid] = s;
  __syncthreads();
  for (int off = 1; off < 1024; off <<= 1) {
    int v = (tid >= off) ? part[tid - off] : 0;
    __syncthreads();
    part[tid] += v;
    __syncthreads();
  }
  int run = (tid == 0) ? 0 : part[tid - 1];
  for (int i = 0; i < CH; ++i) {
    int idx = base + i;
    if (idx < N_NODES) {
      indptr[idx] = run;
      run += counts[idx];
      if (idx == N_NODES - 1) indptr[N_NODES] = run;
    }
  }
}

__global__ void fill_adj(const int* __restrict__ src, const int* __restrict__ dst,
                         const int* __restrict__ indptr, int* __restrict__ cursor,
                         int* __restrict__ adjsrc) {
  int k = blockIdx.x * blockDim.x + threadIdx.x;
  if (k < N_EDGES) {
    int d = dst[k];
    int pos = atomicAdd(&cursor[d], 1);
    adjsrc[indptr[d] + pos] = src[k];
  }
}

// ================= GAT edge softmax + aggregate (wave per dst), bf16 payload =================
// R5 champion: two-pass softmax + 4 row-gathers in flight.
__global__ __launch_bounds__(256) void gat_aggregate_bf(
    const unsigned short* __restrict__ zbf, const float* __restrict__ el,
    const float* __restrict__ er, const int* __restrict__ indptr,
    const int* __restrict__ adjsrc, const float* __restrict__ bias,
    unsigned short* __restrict__ out_bf) {
  int v = (blockIdx.x * blockDim.x + threadIdx.x) >> 6;
  int lane = threadIdx.x & 63;
  if (v >= N_NODES) return;
  int begin = indptr[v], end = indptr[v + 1];
  float er_v = er[v];

  float m = -INFINITY;
  for (int j = begin + lane; j < end; j += 64) {
    float e = el[adjsrc[j]] + er_v;
    e = (e >= 0.f) ? e : NEG_SLOPE * e;
    m = fmaxf(m, e);
  }
  m = waveReduceMax(m);

  float ssum = 0.f;
  for (int j = begin + lane; j < end; j += 64) {
    float e = el[adjsrc[j]] + er_v;
    e = (e >= 0.f) ? e : NEG_SLOPE * e;
    ssum += __expf(e - m);
  }
  float denom = waveReduceSum(ssum);
  float inv = (end > begin) ? 1.f / denom : 0.f;

  float acc[8] = {};
  for (int c = begin; c < end; c += 64) {
    int cc = min(64, end - c);
    int has = (c + lane < end);
    int sIdx = has ? adjsrc[c + lane] : 0;
    float e = has ? el[sIdx] + er_v : 0.f;
    e = (e >= 0.f) ? e : NEG_SLOPE * e;
    float wl = has ? __expf(e - m) * inv : 0.f;
    int t = 0;
    for (; t + 4 <= cc; t += 4) {
      int s0 = __shfl(sIdx, t + 0), s1 = __shfl(sIdx, t + 1);
      int s2 = __shfl(sIdx, t + 2), s3 = __shfl(sIdx, t + 3);
      float w0 = __shfl(wl, t + 0), w1 = __shfl(wl, t + 1);
      float w2 = __shfl(wl, t + 2), w3 = __shfl(wl, t + 3);
      uint4 z0 = ((const uint4*)(zbf + (size_t)s0 * DIM_H))[lane];
      uint4 z1 = ((const uint4*)(zbf + (size_t)s1 * DIM_H))[lane];
      uint4 z2 = ((const uint4*)(zbf + (size_t)s2 * DIM_H))[lane];
      uint4 z3 = ((const uint4*)(zbf + (size_t)s3 * DIM_H))[lane];
      float f0[8], f1[8], f2[8], f3[8];
      unpack8(z0, f0); unpack8(z1, f1); unpack8(z2, f2); unpack8(z3, f3);
#pragma unroll
      for (int i = 0; i < 8; ++i)
        acc[i] += w0 * f0[i] + w1 * f1[i] + w2 * f2[i] + w3 * f3[i];
    }
    for (; t < cc; ++t) {
      int s0 = __shfl(sIdx, t);
      float w0 = __shfl(wl, t);
      uint4 z0 = ((const uint4*)(zbf + (size_t)s0 * DIM_H))[lane];
      float f0[8];
      unpack8(z0, f0);
#pragma unroll
      for (int i = 0; i < 8; ++i) acc[i] += w0 * f0[i];
    }
  }
  const float4* b4 = (const float4*)(bias + lane * 8);
  float4 b0 = b4[0], b1 = b4[1];
  float o[8] = {acc[0] + b0.x, acc[1] + b0.y, acc[2] + b0.z, acc[3] + b0.w,
                acc[4] + b1.x, acc[5] + b1.y, acc[6] + b1.z, acc[7] + b1.w};
  ((uint4*)(out_bf + (size_t)v * DIM_H))[lane] = pack8(o);
}

// ======== A_hat hop (bf16 payload, fp32 accumulate), 4 rows in flight (R5 champion) ========
__global__ __launch_bounds__(256) void propagate_bf(const unsigned short* __restrict__ zin,
                                                    const int* __restrict__ indptr,
                                                    const int* __restrict__ adjsrc,
                                                    unsigned short* __restrict__ out_bf,
                                                    float* __restrict__ out_f32) {
  int v = (blockIdx.x * blockDim.x + threadIdx.x) >> 6;
  int lane = threadIdx.x & 63;
  if (v >= N_NODES) return;
  uint4 sv = ((const uint4*)(zin + (size_t)v * DIM_H))[lane];
  float acc[8];
  unpack8(sv, acc);
  int begin = indptr[v], end = indptr[v + 1];
  for (int c = begin; c < end; c += 64) {
    int cc = min(64, end - c);
    int sIdx = (c + lane < end) ? adjsrc[c + lane] : 0;
    int t = 0;
    for (; t + 4 <= cc; t += 4) {
      int s0 = __shfl(sIdx, t + 0), s1 = __shfl(sIdx, t + 1);
      int s2 = __shfl(sIdx, t + 2), s3 = __shfl(sIdx, t + 3);
      uint4 z0 = ((const uint4*)(zin + (size_t)s0 * DIM_H))[lane];
      uint4 z1 = ((const uint4*)(zin + (size_t)s1 * DIM_H))[lane];
      uint4 z2 = ((const uint4*)(zin + (size_t)s2 * DIM_H))[lane];
      uint4 z3 = ((const uint4*)(zin + (size_t)s3 * DIM_H))[lane];
      float f0[8], f1[8], f2[8], f3[8];
      unpack8(z0, f0); unpack8(z1, f1); unpack8(z2, f2); unpack8(z3, f3);
#pragma unroll
      for (int i = 0; i < 8; ++i) acc[i] += f0[i] + f1[i] + f2[i] + f3[i];
    }
    for (; t < cc; ++t) {
      int s0 = __shfl(sIdx, t);
      uint4 z0 = ((const uint4*)(zin + (size_t)s0 * DIM_H))[lane];
      float f0[8];
      unpack8(z0, f0);
#pragma unroll
      for (int i = 0; i < 8; ++i) acc[i] += f0[i];
    }
  }
  if (out_bf) {
    ((uint4*)(out_bf + (size_t)v * DIM_H))[lane] = pack8(acc);
  } else {
    float4* fr = (float4*)(out_f32 + (size_t)v * DIM_H + lane * 8);
    fr[0] = make_float4(acc[0], acc[1], acc[2], acc[3]);
    fr[1] = make_float4(acc[4], acc[5], acc[6], acc[7]);
  }
}

// ================= launch =================
extern "C" void kernel_launch(void* const* d_in, const int* in_sizes, int n_in,
                              void* d_out, int out_size, void* d_ws, size_t ws_size,
                              hipStream_t stream) {
  const float* feat = (const float*)d_in[0];
  const float* fc_W = (const float*)d_in[1];
  const float* fc_b = (const float*)d_in[2];
  const float* gat_W = (const float*)d_in[3];
  const float* gat_al = (const float*)d_in[4];
  const float* gat_ar = (const float*)d_in[5];
  const float* gat_b = (const float*)d_in[6];
  // d_in[7] = beta unused (reference returns Z_prev)
  const int* src = (const int*)d_in[8];
  const int* dst = (const int*)d_in[9];
  float* out = (float*)d_out;

  char* w = (char*)d_ws;
  auto alloc = [&](size_t bytes) {
    char* p = w;
    w += (bytes + 255) & ~(size_t)255;
    return p;
  };
  unsigned short* hbf   = (unsigned short*)alloc((size_t)M_PAD * DIM_H * 2);
  unsigned short* fcWt  = (unsigned short*)alloc((size_t)DIM_H * DIM_IN * 2);
  unsigned short* gatWt = (unsigned short*)alloc((size_t)NUM_GNNS * DIM_H * DIM_H * 2);
  float* el    = (float*)alloc((size_t)2 * M_PAD * 4);
  float* er    = el + M_PAD;
  // el/er partials: 8 slots each (4 col-blocks x 2 waves), [slot][M_PAD]
  // In-kernel addressing: elp + blockIdx.x*M_PAD + wn*4*M_PAD + row
  //  -> slot = wn*4 + blockIdx.x, covering slots 0..7. Disjoint, no atomics.
  float* elp   = (float*)alloc((size_t)8 * M_PAD * 4);
  float* erp   = (float*)alloc((size_t)8 * M_PAD * 4);
  int* counts  = (int*)alloc((size_t)2 * N_NODES * 4);   // counts+cursor contiguous (R2 lesson)
  int* cursor  = counts + N_NODES;
  int* indptr  = (int*)alloc((size_t)(N_NODES + 1) * 4);
  int* adjsrc  = (int*)alloc((size_t)N_EDGES * 4);
  char* uni = alloc((size_t)M_PAD * DIM_IN * 2);   // Abf (30.9 MB), later Z1 (20.6 MB)
  unsigned short* Abf = (unsigned short*)uni;
  unsigned short* Z1  = (unsigned short*)uni;
  unsigned short* zbf = (unsigned short*)d_out;

  // ---- CSR build ----
  hipMemsetAsync(counts, 0, sizeof(int) * 2 * N_NODES, stream);
  count_edges<<<(N_EDGES + 255) / 256, 256, 0, stream>>>(dst, counts);
  scan_kernel<<<1, 1024, 0, stream>>>(counts, indptr);
  fill_adj<<<(N_EDGES + 255) / 256, 256, 0, stream>>>(src, dst, indptr, cursor, adjsrc);

  // ---- bf16 prep ----
  convert_feat<<<(M_PAD * DIM_IN / 8 + 255) / 256, 256, 0, stream>>>(feat, Abf);
  transpose_bf16<<<dim3((DIM_IN + 255) / 256, DIM_H, 1), 256, 0, stream>>>(fc_W, fcWt, DIM_IN, DIM_H);
  transpose_bf16<<<dim3((DIM_H + 255) / 256, DIM_H, NUM_GNNS), 256, 0, stream>>>(gat_W, gatWt, DIM_H, DIM_H);

  dim3 ggrid(DIM_H / 128, M_PAD / 128);  // (4, 157)

  gemm_mfma_bf16<<<ggrid, 256, 0, stream>>>(Abf, fcWt, fc_b, hbf, DIM_IN,
                                            nullptr, nullptr, nullptr, nullptr);

  int nwaveblocks = (N_NODES * 64 + 255) / 256;
  for (int l = 0; l < NUM_GNNS; ++l) {
    gemm_mfma_bf16<<<ggrid, 256, 0, stream>>>(hbf, gatWt + (size_t)l * DIM_H * DIM_H,
                                              nullptr, zbf, DIM_H,
                                              gat_al + (size_t)l * DIM_H,
                                              gat_ar + (size_t)l * DIM_H, elp, erp);
    eler_reduce<<<(N_NODES + 255) / 256, 256, 0, stream>>>(elp, erp, el, er);
    gat_aggregate_bf<<<nwaveblocks, 256, 0, stream>>>(
        zbf, el, er, indptr, adjsrc, gat_b + (size_t)l * DIM_H, hbf);
  }

  // ---- 3 propagation hops, bf16 payloads, fp32 accumulate ----
  propagate_bf<<<nwaveblocks, 256, 0, stream>>>(hbf, indptr, adjsrc, Z1, nullptr);
  propagate_bf<<<nwaveblocks, 256, 0, stream>>>(Z1, indptr, adjsrc, hbf, nullptr);
  propagate_bf<<<nwaveblocks, 256, 0, stream>>>(hbf, indptr, adjsrc, nullptr, out);
}

// Round 9
// 640.144 us; speedup vs baseline: 1.1005x; 1.0897x over previous
//
#include <hip/hip_runtime.h>
#include <math.h>

#define N_NODES 20000
#define M_PAD   20096   // 157 * 128
#define N_EDGES 320000
#define DIM_IN 768
#define DIM_H 512
#define NUM_GNNS 4
#define NEG_SLOPE 0.2f

#define GEMM_TILES 628        // (M_PAD/128) * (DIM_H/128) = 157*4
#define GEMM_GRID  632        // ceil to multiple of 8 for XCD swizzle

typedef __attribute__((ext_vector_type(8))) short short8;
typedef __attribute__((ext_vector_type(4))) float f32x4;

#define GPTR(p) (const __attribute__((address_space(1))) void*)(p)
#define LPTR(p) (__attribute__((address_space(3))) void*)(p)

__device__ __forceinline__ float bf2f(unsigned int lo16) {
  return __uint_as_float(lo16 << 16);
}
__device__ __forceinline__ unsigned short f2bf(float f) {
  unsigned int u = __float_as_uint(f);
  u += 0x7FFFu + ((u >> 16) & 1u);   // round-to-nearest-even
  return (unsigned short)(u >> 16);
}
__device__ __forceinline__ void unpack8(uint4 v, float* f) {
  f[0] = bf2f(v.x & 0xffffu); f[1] = bf2f(v.x >> 16);
  f[2] = bf2f(v.y & 0xffffu); f[3] = bf2f(v.y >> 16);
  f[4] = bf2f(v.z & 0xffffu); f[5] = bf2f(v.z >> 16);
  f[6] = bf2f(v.w & 0xffffu); f[7] = bf2f(v.w >> 16);
}
__device__ __forceinline__ uint4 pack8(const float* o) {
  uint4 pv;
  pv.x = (unsigned)f2bf(o[0]) | ((unsigned)f2bf(o[1]) << 16);
  pv.y = (unsigned)f2bf(o[2]) | ((unsigned)f2bf(o[3]) << 16);
  pv.z = (unsigned)f2bf(o[4]) | ((unsigned)f2bf(o[5]) << 16);
  pv.w = (unsigned)f2bf(o[6]) | ((unsigned)f2bf(o[7]) << 16);
  return pv;
}

__device__ __forceinline__ float waveReduceSum(float v) {
#pragma unroll
  for (int off = 32; off > 0; off >>= 1) v += __shfl_xor(v, off, 64);
  return v;
}
__device__ __forceinline__ float waveReduceMax(float v) {
#pragma unroll
  for (int off = 32; off > 0; off >>= 1) v = fmaxf(v, __shfl_xor(v, off, 64));
  return v;
}

// ================= MFMA GEMM (lean, R5 epilogue) + XCD tile swizzle =================
// Cbf[M_PAD,512](bf16) = A[M_PAD,K](bf16) @ Bt[512,K]^T (+bias)
// 1-D grid of GEMM_GRID blocks; blocks with the same (bid%8) — dispatched to the
// same XCD — process contiguous row-tiles with all 4 col-tiles back-to-back, so
// each 128xK A-tile is fetched from HBM once per XCD and L2-served thereafter.
__global__ __launch_bounds__(256) void gemm_mfma_bf16(
    const unsigned short* __restrict__ A,
    const unsigned short* __restrict__ Bt,
    const float* __restrict__ bias,
    unsigned short* __restrict__ Cbf,
    int K) {
  int bid = blockIdx.x;
  int tile = (bid & 7) * (GEMM_GRID / 8) + (bid >> 3);
  if (tile >= GEMM_TILES) return;
  int brow = tile >> 2;   // 0..156
  int bcol = tile & 3;    // 0..3

  __shared__ __align__(16) unsigned short As[128 * 32];
  __shared__ __align__(16) unsigned short Bs[128 * 32];
  int tid = threadIdx.x;
  int wave = tid >> 6, lane = tid & 63;
  int wm = wave >> 1, wn = wave & 1;

  int rl = lane >> 2;
  int kc = (lane & 3) ^ ((lane >> 3) & 3);
  int r0 = 32 * wave;
  const unsigned short* gA0 = A + (size_t)(brow * 128 + r0 + rl) * K + kc * 8;
  const unsigned short* gA1 = gA0 + (size_t)16 * K;
  const unsigned short* gB0 = Bt + (size_t)(bcol * 128 + r0 + rl) * K + kc * 8;
  const unsigned short* gB1 = gB0 + (size_t)16 * K;
  unsigned short* lA0 = As + r0 * 32;
  unsigned short* lA1 = As + (r0 + 16) * 32;
  unsigned short* lB0 = Bs + r0 * 32;
  unsigned short* lB1 = Bs + (r0 + 16) * 32;

  int mrow = lane & 15;
  int q = lane >> 4;
  int swz = (q ^ ((mrow >> 1) & 3)) * 8;
  const short8* ra = (const short8*)(As + (64 * wm + mrow) * 32 + swz);
  const short8* rb = (const short8*)(Bs + (64 * wn + mrow) * 32 + swz);

  f32x4 acc[4][4];
#pragma unroll
  for (int i = 0; i < 4; ++i)
#pragma unroll
    for (int j = 0; j < 4; ++j) acc[i][j] = (f32x4)(0.f);

  for (int k0 = 0; k0 < K; k0 += 32) {
    __syncthreads();
    __builtin_amdgcn_global_load_lds(GPTR(gA0 + k0), LPTR(lA0), 16, 0, 0);
    __builtin_amdgcn_global_load_lds(GPTR(gA1 + k0), LPTR(lA1), 16, 0, 0);
    __builtin_amdgcn_global_load_lds(GPTR(gB0 + k0), LPTR(lB0), 16, 0, 0);
    __builtin_amdgcn_global_load_lds(GPTR(gB1 + k0), LPTR(lB1), 16, 0, 0);
    __syncthreads();
    short8 a[4], b[4];
#pragma unroll
    for (int t = 0; t < 4; ++t) a[t] = ra[t * 64];
#pragma unroll
    for (int t = 0; t < 4; ++t) b[t] = rb[t * 64];
#pragma unroll
    for (int mt = 0; mt < 4; ++mt)
#pragma unroll
      for (int nt = 0; nt < 4; ++nt)
        acc[mt][nt] = __builtin_amdgcn_mfma_f32_16x16x32_bf16(a[mt], b[nt], acc[mt][nt], 0, 0, 0);
  }

  int colb = bcol * 128 + 64 * wn + (lane & 15);
  int rowb = brow * 128 + 64 * wm + 4 * q;
#pragma unroll
  for (int nt = 0; nt < 4; ++nt) {
    int col = colb + 16 * nt;
    float bv = bias ? bias[col] : 0.f;
#pragma unroll
    for (int mt = 0; mt < 4; ++mt) {
      int row = rowb + 16 * mt;
#pragma unroll
      for (int i = 0; i < 4; ++i)
        Cbf[(size_t)(row + i) * DIM_H + col] = f2bf(acc[mt][nt][i] + bv);
    }
  }
}

// ================= conversions =================
__global__ void convert_feat(const float* __restrict__ feat, unsigned short* __restrict__ Abf) {
  int t = blockIdx.x * blockDim.x + threadIdx.x;
  const int CHUNKS = M_PAD * DIM_IN / 8;
  if (t >= CHUNKS) return;
  int row = t / (DIM_IN / 8);
  uint4 o;
  if (row < N_NODES) {
    const float4* p = (const float4*)(feat + (size_t)t * 8);
    float4 x = p[0], y = p[1];
    o.x = (unsigned)f2bf(x.x) | ((unsigned)f2bf(x.y) << 16);
    o.y = (unsigned)f2bf(x.z) | ((unsigned)f2bf(x.w) << 16);
    o.z = (unsigned)f2bf(y.x) | ((unsigned)f2bf(y.y) << 16);
    o.w = (unsigned)f2bf(y.z) | ((unsigned)f2bf(y.w) << 16);
  } else {
    o = make_uint4(0, 0, 0, 0);
  }
  ((uint4*)Abf)[t] = o;
}

// LDS-tiled transpose: in [R,C] f32 -> out [C,R] bf16. R,C multiples of 32.
// block (32,8), grid (R/32, C/32, batch). Coalesced reads AND writes.
__global__ __launch_bounds__(256) void transpose_bf16(const float* __restrict__ in,
                                                      unsigned short* __restrict__ out,
                                                      int R, int C) {
  __shared__ float tile[32][33];
  int tx = threadIdx.x, ty = threadIdx.y;
  size_t base = (size_t)blockIdx.z * R * C;
  int r0 = blockIdx.x * 32, c0 = blockIdx.y * 32;
#pragma unroll
  for (int i = 0; i < 4; ++i) {
    int r = r0 + ty + i * 8;
    tile[ty + i * 8][tx] = in[base + (size_t)r * C + c0 + tx];
  }
  __syncthreads();
#pragma unroll
  for (int i = 0; i < 4; ++i) {
    int c = c0 + ty + i * 8;
    out[base + (size_t)c * R + r0 + tx] = f2bf(tile[tx][ty + i * 8]);
  }
}

// ================= CSR build (dst -> src adjacency) =================
__global__ void count_edges(const int* __restrict__ dst, int* __restrict__ counts) {
  int k = blockIdx.x * blockDim.x + threadIdx.x;
  if (k < N_EDGES) atomicAdd(&counts[dst[k]], 1);
}

__global__ __launch_bounds__(1024) void scan_kernel(const int* __restrict__ counts,
                                                    int* __restrict__ indptr) {
  __shared__ int part[1024];
  int tid = threadIdx.x;
  const int CH = (N_NODES + 1023) / 1024;
  int base = tid * CH;
  int s = 0;
  for (int i = 0; i < CH; ++i) {
    int idx = base + i;
    if (idx < N_NODES) s += counts[idx];
  }
  part[tid] = s;
  __syncthreads();
  for (int off = 1; off < 1024; off <<= 1) {
    int v = (tid >= off) ? part[tid - off] : 0;
    __syncthreads();
    part[tid] += v;
    __syncthreads();
  }
  int run = (tid == 0) ? 0 : part[tid - 1];
  for (int i = 0; i < CH; ++i) {
    int idx = base + i;
    if (idx < N_NODES) {
      indptr[idx] = run;
      run += counts[idx];
      if (idx == N_NODES - 1) indptr[N_NODES] = run;
    }
  }
}

__global__ void fill_adj(const int* __restrict__ src, const int* __restrict__ dst,
                         const int* __restrict__ indptr, int* __restrict__ cursor,
                         int* __restrict__ adjsrc) {
  int k = blockIdx.x * blockDim.x + threadIdx.x;
  if (k < N_EDGES) {
    int d = dst[k];
    int pos = atomicAdd(&cursor[d], 1);
    adjsrc[indptr[d] + pos] = src[k];
  }
}

// ================= el/er from bf16 z (lean R5 version) =================
__global__ __launch_bounds__(256) void eler_bf(const unsigned short* __restrict__ zbf,
                                               const float* __restrict__ al,
                                               const float* __restrict__ ar,
                                               float* __restrict__ el, float* __restrict__ er) {
  int wid = (blockIdx.x * blockDim.x + threadIdx.x) >> 6;
  int lane = threadIdx.x & 63;
  if (wid >= N_NODES) return;
  uint4 zv = ((const uint4*)(zbf + (size_t)wid * DIM_H))[lane];
  float z[8];
  unpack8(zv, z);
  const float4* al4 = (const float4*)(al + lane * 8);
  const float4* ar4 = (const float4*)(ar + lane * 8);
  float4 a0 = al4[0], a1 = al4[1], r0 = ar4[0], r1 = ar4[1];
  float sl = z[0] * a0.x + z[1] * a0.y + z[2] * a0.z + z[3] * a0.w +
             z[4] * a1.x + z[5] * a1.y + z[6] * a1.z + z[7] * a1.w;
  float sr = z[0] * r0.x + z[1] * r0.y + z[2] * r0.z + z[3] * r0.w +
             z[4] * r1.x + z[5] * r1.y + z[6] * r1.z + z[7] * r1.w;
  sl = waveReduceSum(sl);
  sr = waveReduceSum(sr);
  if (lane == 0) { el[wid] = sl; er[wid] = sr; }
}

// ================= GAT edge softmax + aggregate (R5 champion) =================
__global__ __launch_bounds__(256) void gat_aggregate_bf(
    const unsigned short* __restrict__ zbf, const float* __restrict__ el,
    const float* __restrict__ er, const int* __restrict__ indptr,
    const int* __restrict__ adjsrc, const float* __restrict__ bias,
    unsigned short* __restrict__ out_bf) {
  int v = (blockIdx.x * blockDim.x + threadIdx.x) >> 6;
  int lane = threadIdx.x & 63;
  if (v >= N_NODES) return;
  int begin = indptr[v], end = indptr[v + 1];
  float er_v = er[v];

  float m = -INFINITY;
  for (int j = begin + lane; j < end; j += 64) {
    float e = el[adjsrc[j]] + er_v;
    e = (e >= 0.f) ? e : NEG_SLOPE * e;
    m = fmaxf(m, e);
  }
  m = waveReduceMax(m);

  float ssum = 0.f;
  for (int j = begin + lane; j < end; j += 64) {
    float e = el[adjsrc[j]] + er_v;
    e = (e >= 0.f) ? e : NEG_SLOPE * e;
    ssum += __expf(e - m);
  }
  float denom = waveReduceSum(ssum);
  float inv = (end > begin) ? 1.f / denom : 0.f;

  float acc[8] = {};
  for (int c = begin; c < end; c += 64) {
    int cc = min(64, end - c);
    int has = (c + lane < end);
    int sIdx = has ? adjsrc[c + lane] : 0;
    float e = has ? el[sIdx] + er_v : 0.f;
    e = (e >= 0.f) ? e : NEG_SLOPE * e;
    float wl = has ? __expf(e - m) * inv : 0.f;
    int t = 0;
    for (; t + 4 <= cc; t += 4) {
      int s0 = __shfl(sIdx, t + 0), s1 = __shfl(sIdx, t + 1);
      int s2 = __shfl(sIdx, t + 2), s3 = __shfl(sIdx, t + 3);
      float w0 = __shfl(wl, t + 0), w1 = __shfl(wl, t + 1);
      float w2 = __shfl(wl, t + 2), w3 = __shfl(wl, t + 3);
      uint4 z0 = ((const uint4*)(zbf + (size_t)s0 * DIM_H))[lane];
      uint4 z1 = ((const uint4*)(zbf + (size_t)s1 * DIM_H))[lane];
      uint4 z2 = ((const uint4*)(zbf + (size_t)s2 * DIM_H))[lane];
      uint4 z3 = ((const uint4*)(zbf + (size_t)s3 * DIM_H))[lane];
      float f0[8], f1[8], f2[8], f3[8];
      unpack8(z0, f0); unpack8(z1, f1); unpack8(z2, f2); unpack8(z3, f3);
#pragma unroll
      for (int i = 0; i < 8; ++i)
        acc[i] += w0 * f0[i] + w1 * f1[i] + w2 * f2[i] + w3 * f3[i];
    }
    for (; t < cc; ++t) {
      int s0 = __shfl(sIdx, t);
      float w0 = __shfl(wl, t);
      uint4 z0 = ((const uint4*)(zbf + (size_t)s0 * DIM_H))[lane];
      float f0[8];
      unpack8(z0, f0);
#pragma unroll
      for (int i = 0; i < 8; ++i) acc[i] += w0 * f0[i];
    }
  }
  const float4* b4 = (const float4*)(bias + lane * 8);
  float4 b0 = b4[0], b1 = b4[1];
  float o[8] = {acc[0] + b0.x, acc[1] + b0.y, acc[2] + b0.z, acc[3] + b0.w,
                acc[4] + b1.x, acc[5] + b1.y, acc[6] + b1.z, acc[7] + b1.w};
  ((uint4*)(out_bf + (size_t)v * DIM_H))[lane] = pack8(o);
}

// ======== A_hat hop (bf16 payload, fp32 accumulate), 4 rows in flight (R5 champion) ========
__global__ __launch_bounds__(256) void propagate_bf(const unsigned short* __restrict__ zin,
                                                    const int* __restrict__ indptr,
                                                    const int* __restrict__ adjsrc,
                                                    unsigned short* __restrict__ out_bf,
                                                    float* __restrict__ out_f32) {
  int v = (blockIdx.x * blockDim.x + threadIdx.x) >> 6;
  int lane = threadIdx.x & 63;
  if (v >= N_NODES) return;
  uint4 sv = ((const uint4*)(zin + (size_t)v * DIM_H))[lane];
  float acc[8];
  unpack8(sv, acc);
  int begin = indptr[v], end = indptr[v + 1];
  for (int c = begin; c < end; c += 64) {
    int cc = min(64, end - c);
    int sIdx = (c + lane < end) ? adjsrc[c + lane] : 0;
    int t = 0;
    for (; t + 4 <= cc; t += 4) {
      int s0 = __shfl(sIdx, t + 0), s1 = __shfl(sIdx, t + 1);
      int s2 = __shfl(sIdx, t + 2), s3 = __shfl(sIdx, t + 3);
      uint4 z0 = ((const uint4*)(zin + (size_t)s0 * DIM_H))[lane];
      uint4 z1 = ((const uint4*)(zin + (size_t)s1 * DIM_H))[lane];
      uint4 z2 = ((const uint4*)(zin + (size_t)s2 * DIM_H))[lane];
      uint4 z3 = ((const uint4*)(zin + (size_t)s3 * DIM_H))[lane];
      float f0[8], f1[8], f2[8], f3[8];
      unpack8(z0, f0); unpack8(z1, f1); unpack8(z2, f2); unpack8(z3, f3);
#pragma unroll
      for (int i = 0; i < 8; ++i) acc[i] += f0[i] + f1[i] + f2[i] + f3[i];
    }
    for (; t < cc; ++t) {
      int s0 = __shfl(sIdx, t);
      uint4 z0 = ((const uint4*)(zin + (size_t)s0 * DIM_H))[lane];
      float f0[8];
      unpack8(z0, f0);
#pragma unroll
      for (int i = 0; i < 8; ++i) acc[i] += f0[i];
    }
  }
  if (out_bf) {
    ((uint4*)(out_bf + (size_t)v * DIM_H))[lane] = pack8(acc);
  } else {
    float4* fr = (float4*)(out_f32 + (size_t)v * DIM_H + lane * 8);
    fr[0] = make_float4(acc[0], acc[1], acc[2], acc[3]);
    fr[1] = make_float4(acc[4], acc[5], acc[6], acc[7]);
  }
}

// ================= launch =================
extern "C" void kernel_launch(void* const* d_in, const int* in_sizes, int n_in,
                              void* d_out, int out_size, void* d_ws, size_t ws_size,
                              hipStream_t stream) {
  const float* feat = (const float*)d_in[0];
  const float* fc_W = (const float*)d_in[1];
  const float* fc_b = (const float*)d_in[2];
  const float* gat_W = (const float*)d_in[3];
  const float* gat_al = (const float*)d_in[4];
  const float* gat_ar = (const float*)d_in[5];
  const float* gat_b = (const float*)d_in[6];
  // d_in[7] = beta unused (reference returns Z_prev)
  const int* src = (const int*)d_in[8];
  const int* dst = (const int*)d_in[9];
  float* out = (float*)d_out;

  char* w = (char*)d_ws;
  auto alloc = [&](size_t bytes) {
    char* p = w;
    w += (bytes + 255) & ~(size_t)255;
    return p;
  };
  unsigned short* hbf   = (unsigned short*)alloc((size_t)M_PAD * DIM_H * 2);
  unsigned short* fcWt  = (unsigned short*)alloc((size_t)DIM_H * DIM_IN * 2);
  unsigned short* gatWt = (unsigned short*)alloc((size_t)NUM_GNNS * DIM_H * DIM_H * 2);
  float* el    = (float*)alloc((size_t)N_NODES * 4);
  float* er    = (float*)alloc((size_t)N_NODES * 4);
  int* counts  = (int*)alloc((size_t)2 * N_NODES * 4);   // counts+cursor contiguous (R2 lesson)
  int* cursor  = counts + N_NODES;
  int* indptr  = (int*)alloc((size_t)(N_NODES + 1) * 4);
  int* adjsrc  = (int*)alloc((size_t)N_EDGES * 4);
  char* uni = alloc((size_t)M_PAD * DIM_IN * 2);   // Abf (30.9 MB), later Z1 (20.6 MB)
  unsigned short* Abf = (unsigned short*)uni;
  unsigned short* Z1  = (unsigned short*)uni;
  unsigned short* zbf = (unsigned short*)d_out;

  // ---- CSR build ----
  hipMemsetAsync(counts, 0, sizeof(int) * 2 * N_NODES, stream);
  count_edges<<<(N_EDGES + 255) / 256, 256, 0, stream>>>(dst, counts);
  scan_kernel<<<1, 1024, 0, stream>>>(counts, indptr);
  fill_adj<<<(N_EDGES + 255) / 256, 256, 0, stream>>>(src, dst, indptr, cursor, adjsrc);

  // ---- bf16 prep ----
  convert_feat<<<(M_PAD * DIM_IN / 8 + 255) / 256, 256, 0, stream>>>(feat, Abf);
  transpose_bf16<<<dim3(DIM_IN / 32, DIM_H / 32, 1), dim3(32, 8), 0, stream>>>(fc_W, fcWt, DIM_IN, DIM_H);
  transpose_bf16<<<dim3(DIM_H / 32, DIM_H / 32, NUM_GNNS), dim3(32, 8), 0, stream>>>(gat_W, gatWt, DIM_H, DIM_H);

  gemm_mfma_bf16<<<GEMM_GRID, 256, 0, stream>>>(Abf, fcWt, fc_b, hbf, DIM_IN);

  int nwaveblocks = (N_NODES * 64 + 255) / 256;
  for (int l = 0; l < NUM_GNNS; ++l) {
    gemm_mfma_bf16<<<GEMM_GRID, 256, 0, stream>>>(hbf, gatWt + (size_t)l * DIM_H * DIM_H,
                                                  nullptr, zbf, DIM_H);
    eler_bf<<<nwaveblocks, 256, 0, stream>>>(zbf, gat_al + (size_t)l * DIM_H,
                                             gat_ar + (size_t)l * DIM_H, el, er);
    gat_aggregate_bf<<<nwaveblocks, 256, 0, stream>>>(
        zbf, el, er, indptr, adjsrc, gat_b + (size_t)l * DIM_H, hbf);
  }

  // ---- 3 propagation hops, bf16 payloads, fp32 accumulate ----
  propagate_bf<<<nwaveblocks, 256, 0, stream>>>(hbf, indptr, adjsrc, Z1, nullptr);
  propagate_bf<<<nwaveblocks, 256, 0, stream>>>(Z1, indptr, adjsrc, hbf, nullptr);
  propagate_bf<<<nwaveblocks, 256, 0, stream>>>(hbf, indptr, adjsrc, nullptr, out);
}